// Round 3
// baseline (290.024 us; speedup 1.0000x reference)
//
#include <hip/hip_runtime.h>

// Problem constants (fixed by setup_inputs) — ALL TENSORS ARE FLOAT32.
#define B 4
#define H 16
#define S 2048
#define D 64
#define M 1000
#define TOPKN 10
#define HID 1024   // H*D

// Flat output element offsets (f32 elements)
//  out0 inputs  [4,2048,1024]   @ 0
//  out1 q       [4,16,2048,64]  @ 8388608
//  out2 k_aug   [4,16,2058,64]  @ 16777216
//  out3 v_aug   [4,16,2058,64]  @ 25206784
//  out4 mask_aug[4,2058]        @ 33636352
//  out5 seq_len_k scalar        @ 33644584
//  out6 positions_k [4,2058]    @ 33644585   (total 33652817 elems)
#define O4E 33636352U
#define O5E 33644584U
#define O6E 33644585U
// float4-chunk constants (4 f32 = 16 B per chunk)
#define O2C 4194304U   // out2 offset in chunks
#define O3C 6301696U   // out3 offset in chunks
#define BHSTR 32928U   // 2058*64/4 chunks per (b,h) in k_aug/v_aug
#define CF 2097152U    // 8,388,608 elems / 4 per flat region

// Stage-1 grid: 125 sims blocks (8 rows each = M exactly) + 2048 copy blocks.
// Each copy block owns ONE contiguous 4096-chunk (64 KB) tile of ONE region:
// uniform work, block-level region decode, fill-kernel-like streams.
#define NSIMS 125
#define NCOPYBLK 2048
#define TILE 4096u  // chunks per copy block (divides 32768-chunk (b,h) panel)

typedef float f4_t __attribute__((ext_vector_type(4)));

__device__ __forceinline__ void nt_store4(float4* p, float4 v) {
  __builtin_nontemporal_store(*(const f4_t*)&v, (f4_t*)p);
}

// ---------------------------------------------------------------------------
// Stage 1: bulk copy (contiguous tiles, NT stores) + sims[b][m] -> ws.
__global__ __launch_bounds__(256) void fused_stage1(
    const float* __restrict__ in0, const float* __restrict__ qin,
    const float* __restrict__ kin, const float* __restrict__ vin,
    const float* __restrict__ mkeys, float* __restrict__ out,
    float* __restrict__ ws, unsigned int outElems) {
  const int blk = blockIdx.x;
  const int tid = threadIdx.x;

  __shared__ float4 s_q4[B][256];  // 4 query vectors, float4-packed (16 KB)
  __shared__ float s_qn[B];

  if (blk >= NSIMS) {
    // ---- copy block: one contiguous 4096-chunk tile of one region ----
    const unsigned int outChunks = outElems >> 2;
    const int t = blk - NSIMS;          // 0..2047
    const int region = t >> 9;          // 512 tiles per 2M-chunk region
    const unsigned int tileBase = (unsigned int)(t & 511) * TILE;

    const float4* src;
    unsigned int dstBase;
    if (region == 0) {
      src = (const float4*)in0 + tileBase;
      dstBase = tileBase;                       // out0
    } else if (region == 1) {
      src = (const float4*)qin + tileBase;
      dstBase = CF + tileBase;                  // out1
    } else {
      src = ((region == 2) ? (const float4*)kin : (const float4*)vin) +
            tileBase;
      unsigned int bh = tileBase >> 15;         // 32768 chunks per (b,h)
      unsigned int r = tileBase & 32767u;       // tile-constant (4096|32768)
      dstBase = ((region == 2) ? O2C : O3C) + bh * BHSTR + 160u + r;
    }

    float4* o = (float4*)out;
    // 16 chunks/thread: 2 batches of {8 loads in flight -> 8 NT stores}.
#pragma unroll
    for (int half = 0; half < 2; ++half) {
      float4 v0 = src[tid + (half * 8 + 0) * 256];
      float4 v1 = src[tid + (half * 8 + 1) * 256];
      float4 v2 = src[tid + (half * 8 + 2) * 256];
      float4 v3 = src[tid + (half * 8 + 3) * 256];
      float4 v4 = src[tid + (half * 8 + 4) * 256];
      float4 v5 = src[tid + (half * 8 + 5) * 256];
      float4 v6 = src[tid + (half * 8 + 6) * 256];
      float4 v7 = src[tid + (half * 8 + 7) * 256];
      unsigned int d = dstBase + tid + (half * 8) * 256;
      if (d + 0 * 256 < outChunks) nt_store4(o + d + 0 * 256, v0);
      if (d + 1 * 256 < outChunks) nt_store4(o + d + 1 * 256, v1);
      if (d + 2 * 256 < outChunks) nt_store4(o + d + 2 * 256, v2);
      if (d + 3 * 256 < outChunks) nt_store4(o + d + 3 * 256, v3);
      if (d + 4 * 256 < outChunks) nt_store4(o + d + 4 * 256, v4);
      if (d + 5 * 256 < outChunks) nt_store4(o + d + 5 * 256, v5);
      if (d + 6 * 256 < outChunks) nt_store4(o + d + 6 * 256, v6);
      if (d + 7 * 256 < outChunks) nt_store4(o + d + 7 * 256, v7);
    }
  } else {
    // ---- sims block: rows m = blk*8 .. blk*8+7 (125*8 = 1000 = M) ----
    // Load all 4 query vectors: query_key[b][h*64+d] = k[b, h, S-1, d].
    for (int i = tid; i < B * 256; i += 256) {
      int b = i >> 8, c = i & 255;
      int h = c >> 4, dd = (c & 15) << 2;
      s_q4[b][c] = *(const float4*)(kin +
                                    ((size_t)(b * H + h) * S + (S - 1)) * D +
                                    dd);
    }
    __syncthreads();

    const int lane = tid & 63;
    const int w = tid >> 6;  // wave id 0..3

    // q norms: wave w reduces batch w
    {
      float ss = 0.f;
      for (int j = 0; j < 4; ++j) {
        float4 v = s_q4[w][lane + j * 64];
        ss += v.x * v.x + v.y * v.y + v.z * v.z + v.w * v.w;
      }
      for (int off = 32; off; off >>= 1) ss += __shfl_xor(ss, off);
      if (lane == 0) s_qn[w] = sqrtf(ss) + 1e-8f;
    }
    __syncthreads();

    // Each wave: 2 rows; lanes read the 4 KB row coalesced (64x16B chunks).
    const float4* mk4 = (const float4*)mkeys;
    for (int r = 0; r < 2; ++r) {
      const int m = blk * 8 + w * 2 + r;  // always < M
      float d0 = 0.f, d1 = 0.f, d2 = 0.f, d3 = 0.f, msq = 0.f;
#pragma unroll
      for (int j = 0; j < 4; ++j) {
        float4 ch = mk4[(size_t)m * 256 + lane + j * 64];
        float4 q0 = s_q4[0][lane + j * 64];
        float4 q1 = s_q4[1][lane + j * 64];
        float4 q2 = s_q4[2][lane + j * 64];
        float4 q3 = s_q4[3][lane + j * 64];
        d0 += q0.x * ch.x + q0.y * ch.y + q0.z * ch.z + q0.w * ch.w;
        d1 += q1.x * ch.x + q1.y * ch.y + q1.z * ch.z + q1.w * ch.w;
        d2 += q2.x * ch.x + q2.y * ch.y + q2.z * ch.z + q2.w * ch.w;
        d3 += q3.x * ch.x + q3.y * ch.y + q3.z * ch.z + q3.w * ch.w;
        msq += ch.x * ch.x + ch.y * ch.y + ch.z * ch.z + ch.w * ch.w;
      }
      for (int off = 32; off; off >>= 1) {
        d0 += __shfl_xor(d0, off);
        d1 += __shfl_xor(d1, off);
        d2 += __shfl_xor(d2, off);
        d3 += __shfl_xor(d3, off);
        msq += __shfl_xor(msq, off);
      }
      if (lane == 0) {
        float den = sqrtf(msq) + 1e-8f;  // same formula as proven kernel
        ws[0 * 1024 + m] = d0 / (s_qn[0] * den);
        ws[1 * 1024 + m] = d1 / (s_qn[1] * den);
        ws[2 * 1024 + m] = d2 / (s_qn[2] * den);
        ws[3 * 1024 + m] = d3 / (s_qn[3] * den);
      }
    }
  }
}

// ---------------------------------------------------------------------------
// Stage 2: per-batch top-10 from ws + mask/positions/seq_len + gather.
__global__ __launch_bounds__(256) void fused_stage2(
    const float* __restrict__ amask, const float* __restrict__ mkeys,
    const float* __restrict__ mvals, const float* __restrict__ mpos,
    const float* __restrict__ ws, float* __restrict__ out,
    unsigned int outElems) {
  const int b = blockIdx.x;
  const int tid = threadIdx.x;
  const unsigned int outChunks = outElems >> 2;
  const int SK = S + TOPKN;  // 2058

  __shared__ float s_sims[1024];  // sims padded with -inf
  __shared__ float s_rv[256];
  __shared__ int s_ri[256];
  __shared__ int s_top[TOPKN];

  for (int i = tid; i < 1024; i += 256)
    s_sims[i] = (i < M) ? ws[b * 1024 + i] : -INFINITY;

  // mask_aug = [ones(K), mask]; positions_k[0:S] = arange(S)
  for (int i = tid; i < SK; i += 256) {
    unsigned int d4 = O4E + (unsigned int)(b * SK + i);
    if (d4 < outElems)
      out[d4] = (i < TOPKN) ? 1.0f : amask[b * S + (i - TOPKN)];
    unsigned int d6 = O6E + (unsigned int)(b * SK + i);
    if (i < S && d6 < outElems) out[d6] = (float)i;
  }
  if (b == 0 && tid == 0 && O5E < outElems)
    out[O5E] = 2064.0f;  // ref value is bf16-rounded 2058 (proven round 0)
  __syncthreads();

  // top-10: LDS-tree argmax x10 (ties -> lowest index, JAX semantics).
  // bi always a valid in-range index — NaN-proof, no sentinel can escape.
  for (int t = 0; t < TOPKN; ++t) {
    int base = tid * 4;
    float bv = s_sims[base];
    int bi = base;
    for (int j = 1; j < 4; ++j) {
      float v = s_sims[base + j];
      if (v > bv) { bv = v; bi = base + j; }  // '>' keeps lowest index
    }
    s_rv[tid] = bv;
    s_ri[tid] = bi;
    __syncthreads();
    for (int w = 128; w > 0; w >>= 1) {
      if (tid < w) {
        float ov = s_rv[tid + w];
        int oi = s_ri[tid + w];
        if (ov > s_rv[tid] || (ov == s_rv[tid] && oi < s_ri[tid])) {
          s_rv[tid] = ov;
          s_ri[tid] = oi;
        }
      }
      __syncthreads();
    }
    if (tid == 0) {
      int sel = s_ri[0];                     // in [0,1024) by construction
      s_sims[sel] = -INFINITY;
      s_top[t] = (sel < M) ? sel : (M - 1);  // clamp for gather safety
    }
    __syncthreads();
  }

  // r_pos tail of positions_k
  if (tid < TOPKN) {
    unsigned int d6 = O6E + (unsigned int)(b * SK + S + tid);
    if (d6 < outElems) out[d6] = mpos[s_top[tid]];
  }

  // gather retrieved rows: k_aug/v_aug[b,h,kk,:] = mem[im][h*64 .. h*64+63]
  // 2 * H * TOPK * 16 chunks = 5120 chunks per batch.
  const float4* mk4 = (const float4*)mkeys;
  const float4* mv4 = (const float4*)mvals;
  float4* o = (float4*)out;
  for (int c = tid; c < 5120; c += 256) {
    int isv = (c >= 2560);
    int cc = isv ? c - 2560 : c;
    int row = cc >> 4, ch = cc & 15;  // 16 chunks per 64-elem row
    int h = row / 10, kk = row - h * 10;
    int im = s_top[kk];               // clamped to [0, M)
    const float4* src = isv ? mv4 : mk4;
    unsigned int dst = (isv ? O3C : O2C) +
                       (unsigned int)((b * H + h) * BHSTR + kk * 16 + ch);
    if (dst < outChunks) o[dst] = src[(size_t)im * 256 + h * 16 + ch];
  }
}

// ---------------------------------------------------------------------------
extern "C" void kernel_launch(void* const* d_in, const int* in_sizes, int n_in,
                              void* d_out, int out_size, void* d_ws, size_t ws_size,
                              hipStream_t stream) {
  const float* in0 = (const float*)d_in[0];  // inputs  [4,2048,1024]
  const float* q   = (const float*)d_in[1];  // q       [4,16,2048,64]
  const float* k   = (const float*)d_in[2];  // k
  const float* v   = (const float*)d_in[3];  // v
  const float* am  = (const float*)d_in[4];  // attention_mask [4,2048]
  const float* mk  = (const float*)d_in[5];  // mem_keys   [1000,1024]
  const float* mv  = (const float*)d_in[6];  // mem_values [1000,1024]
  const float* mp  = (const float*)d_in[7];  // mem_positions [1000]
  // d_in[8] = seq_len_q (unused; S fixed at 2048)
  (void)in_sizes; (void)n_in; (void)ws_size;

  float* ws = (float*)d_ws;  // needs B*1024*4 = 16 KB; harness ws is larger

  fused_stage1<<<NSIMS + NCOPYBLK, 256, 0, stream>>>(
      in0, q, k, v, mk, (float*)d_out, ws, (unsigned int)out_size);
  fused_stage2<<<B, 256, 0, stream>>>(
      am, mk, mv, mp, ws, (float*)d_out, (unsigned int)out_size);
}

// Round 4
// 288.709 us; speedup vs baseline: 1.0046x; 1.0046x over previous
//
#include <hip/hip_runtime.h>

// Problem constants (fixed by setup_inputs) — ALL TENSORS ARE FLOAT32.
#define B 4
#define H 16
#define S 2048
#define D 64
#define M 1000
#define TOPKN 10
#define HID 1024   // H*D

// Flat output element offsets (f32 elements)
//  out0 inputs  [4,2048,1024]   @ 0
//  out1 q       [4,16,2048,64]  @ 8388608
//  out2 k_aug   [4,16,2058,64]  @ 16777216
//  out3 v_aug   [4,16,2058,64]  @ 25206784
//  out4 mask_aug[4,2058]        @ 33636352
//  out5 seq_len_k scalar        @ 33644584
//  out6 positions_k [4,2058]    @ 33644585   (total 33652817 elems)
#define O4E 33636352U
#define O5E 33644584U
#define O6E 33644585U
// float4-chunk constants (4 f32 = 16 B per chunk)
#define O2C 4194304U   // out2 offset in chunks
#define O3C 6301696U   // out3 offset in chunks
#define BHSTR 32928U   // 2058*64/4 chunks per (b,h) in k_aug/v_aug
#define CF 2097152U    // 8,388,608 elems / 4 per flat region

// Stage-1 grid: 125 sims blocks + 1024 long-lived copy blocks (4 per CU).
// Each copy block owns ONE contiguous 8192-chunk (128 KB) tile of ONE region
// (256 blocks per region; 1024*256*32 = 8,388,608 chunks exactly) and streams
// it with a double-banked software pipeline: 8 loads in flight while 8 stores
// retire, continuously — steady-state read+write overlap, no burst oscillation.
#define NSIMS 125
#define NCOPYBLK 1024
#define TILE 8192u  // chunks per copy block (divides 32768-chunk (b,h) panel)

typedef float f4_t __attribute__((ext_vector_type(4)));

__device__ __forceinline__ void nt_store4(float4* p, float4 v) {
  __builtin_nontemporal_store(*(const f4_t*)&v, (f4_t*)p);
}

// ---------------------------------------------------------------------------
// Stage 1: bulk copy (persistent pipelined tiles) + sims[b][m] -> ws.
__global__ __launch_bounds__(256) void fused_stage1(
    const float* __restrict__ in0, const float* __restrict__ qin,
    const float* __restrict__ kin, const float* __restrict__ vin,
    const float* __restrict__ mkeys, float* __restrict__ out,
    float* __restrict__ ws, unsigned int outElems) {
  const int blk = blockIdx.x;
  const int tid = threadIdx.x;

  __shared__ float4 s_q4[B][256];  // 4 query vectors, float4-packed (16 KB)
  __shared__ float s_qn[B];

  if (blk >= NSIMS) {
    // ---- copy block: one contiguous 8192-chunk tile of one region ----
    const unsigned int outChunks = outElems >> 2;
    const int t = blk - NSIMS;          // 0..1023
    const int region = t >> 8;          // 256 tiles per 2M-chunk region
    const unsigned int tileBase = (unsigned int)(t & 255) * TILE;

    const float4* src;
    unsigned int dstBase;
    if (region == 0) {
      src = (const float4*)in0 + tileBase;
      dstBase = tileBase;                       // out0
    } else if (region == 1) {
      src = (const float4*)qin + tileBase;
      dstBase = CF + tileBase;                  // out1
    } else {
      src = ((region == 2) ? (const float4*)kin : (const float4*)vin) +
            tileBase;
      unsigned int bh = tileBase >> 15;         // 32768 chunks per (b,h)
      unsigned int r = tileBase & 32767u;       // tile-constant (8192|32768)
      dstBase = ((region == 2) ? O2C : O3C) + bh * BHSTR + 160u + r;
    }

    float4* o = (float4*)out;
    // 32 chunks/thread in 4 bursts, double-banked:
    //   load A[0..7] ; load B[0..7] ; store A ; load A' ; store B ; load B' ;
    //   store A' ; store B'  — loads for the next burst are always in flight
    //   while the previous burst's stores retire.
    float4 A[8], Bk[8];
#pragma unroll
    for (int j = 0; j < 8; ++j) A[j] = src[tid + j * 256];
#pragma unroll
    for (int j = 0; j < 8; ++j) Bk[j] = src[tid + (8 + j) * 256];
#pragma unroll
    for (int j = 0; j < 8; ++j) {
      unsigned int d = dstBase + tid + j * 256;
      if (d < outChunks) nt_store4(o + d, A[j]);
    }
#pragma unroll
    for (int j = 0; j < 8; ++j) A[j] = src[tid + (16 + j) * 256];
#pragma unroll
    for (int j = 0; j < 8; ++j) {
      unsigned int d = dstBase + tid + (8 + j) * 256;
      if (d < outChunks) nt_store4(o + d, Bk[j]);
    }
#pragma unroll
    for (int j = 0; j < 8; ++j) Bk[j] = src[tid + (24 + j) * 256];
#pragma unroll
    for (int j = 0; j < 8; ++j) {
      unsigned int d = dstBase + tid + (16 + j) * 256;
      if (d < outChunks) nt_store4(o + d, A[j]);
    }
#pragma unroll
    for (int j = 0; j < 8; ++j) {
      unsigned int d = dstBase + tid + (24 + j) * 256;
      if (d < outChunks) nt_store4(o + d, Bk[j]);
    }
  } else {
    // ---- sims block: rows m = blk*8 .. blk*8+7 (125*8 = 1000 = M) ----
    // Load all 4 query vectors: query_key[b][h*64+d] = k[b, h, S-1, d].
    for (int i = tid; i < B * 256; i += 256) {
      int b = i >> 8, c = i & 255;
      int h = c >> 4, dd = (c & 15) << 2;
      s_q4[b][c] = *(const float4*)(kin +
                                    ((size_t)(b * H + h) * S + (S - 1)) * D +
                                    dd);
    }
    __syncthreads();

    const int lane = tid & 63;
    const int w = tid >> 6;  // wave id 0..3

    // q norms: wave w reduces batch w
    {
      float ss = 0.f;
      for (int j = 0; j < 4; ++j) {
        float4 v = s_q4[w][lane + j * 64];
        ss += v.x * v.x + v.y * v.y + v.z * v.z + v.w * v.w;
      }
      for (int off = 32; off; off >>= 1) ss += __shfl_xor(ss, off);
      if (lane == 0) s_qn[w] = sqrtf(ss) + 1e-8f;
    }
    __syncthreads();

    // Each wave: 2 rows; lanes read the 4 KB row coalesced (64x16B chunks).
    const float4* mk4 = (const float4*)mkeys;
    for (int r = 0; r < 2; ++r) {
      const int m = blk * 8 + w * 2 + r;  // always < M
      float d0 = 0.f, d1 = 0.f, d2 = 0.f, d3 = 0.f, msq = 0.f;
#pragma unroll
      for (int j = 0; j < 4; ++j) {
        float4 ch = mk4[(size_t)m * 256 + lane + j * 64];
        float4 q0 = s_q4[0][lane + j * 64];
        float4 q1 = s_q4[1][lane + j * 64];
        float4 q2 = s_q4[2][lane + j * 64];
        float4 q3 = s_q4[3][lane + j * 64];
        d0 += q0.x * ch.x + q0.y * ch.y + q0.z * ch.z + q0.w * ch.w;
        d1 += q1.x * ch.x + q1.y * ch.y + q1.z * ch.z + q1.w * ch.w;
        d2 += q2.x * ch.x + q2.y * ch.y + q2.z * ch.z + q2.w * ch.w;
        d3 += q3.x * ch.x + q3.y * ch.y + q3.z * ch.z + q3.w * ch.w;
        msq += ch.x * ch.x + ch.y * ch.y + ch.z * ch.z + ch.w * ch.w;
      }
      for (int off = 32; off; off >>= 1) {
        d0 += __shfl_xor(d0, off);
        d1 += __shfl_xor(d1, off);
        d2 += __shfl_xor(d2, off);
        d3 += __shfl_xor(d3, off);
        msq += __shfl_xor(msq, off);
      }
      if (lane == 0) {
        float den = sqrtf(msq) + 1e-8f;  // same formula as proven kernel
        ws[0 * 1024 + m] = d0 / (s_qn[0] * den);
        ws[1 * 1024 + m] = d1 / (s_qn[1] * den);
        ws[2 * 1024 + m] = d2 / (s_qn[2] * den);
        ws[3 * 1024 + m] = d3 / (s_qn[3] * den);
      }
    }
  }
}

// ---------------------------------------------------------------------------
// Stage 2: per-batch top-10 from ws + mask/positions/seq_len + gather.
__global__ __launch_bounds__(256) void fused_stage2(
    const float* __restrict__ amask, const float* __restrict__ mkeys,
    const float* __restrict__ mvals, const float* __restrict__ mpos,
    const float* __restrict__ ws, float* __restrict__ out,
    unsigned int outElems) {
  const int b = blockIdx.x;
  const int tid = threadIdx.x;
  const unsigned int outChunks = outElems >> 2;
  const int SK = S + TOPKN;  // 2058

  __shared__ float s_sims[1024];  // sims padded with -inf
  __shared__ float s_rv[256];
  __shared__ int s_ri[256];
  __shared__ int s_top[TOPKN];

  for (int i = tid; i < 1024; i += 256)
    s_sims[i] = (i < M) ? ws[b * 1024 + i] : -INFINITY;

  // mask_aug = [ones(K), mask]; positions_k[0:S] = arange(S)
  for (int i = tid; i < SK; i += 256) {
    unsigned int d4 = O4E + (unsigned int)(b * SK + i);
    if (d4 < outElems)
      out[d4] = (i < TOPKN) ? 1.0f : amask[b * S + (i - TOPKN)];
    unsigned int d6 = O6E + (unsigned int)(b * SK + i);
    if (i < S && d6 < outElems) out[d6] = (float)i;
  }
  if (b == 0 && tid == 0 && O5E < outElems)
    out[O5E] = 2064.0f;  // ref value is bf16-rounded 2058 (proven round 0)
  __syncthreads();

  // top-10: LDS-tree argmax x10 (ties -> lowest index, JAX semantics).
  // bi always a valid in-range index — NaN-proof, no sentinel can escape.
  for (int t = 0; t < TOPKN; ++t) {
    int base = tid * 4;
    float bv = s_sims[base];
    int bi = base;
    for (int j = 1; j < 4; ++j) {
      float v = s_sims[base + j];
      if (v > bv) { bv = v; bi = base + j; }  // '>' keeps lowest index
    }
    s_rv[tid] = bv;
    s_ri[tid] = bi;
    __syncthreads();
    for (int w = 128; w > 0; w >>= 1) {
      if (tid < w) {
        float ov = s_rv[tid + w];
        int oi = s_ri[tid + w];
        if (ov > s_rv[tid] || (ov == s_rv[tid] && oi < s_ri[tid])) {
          s_rv[tid] = ov;
          s_ri[tid] = oi;
        }
      }
      __syncthreads();
    }
    if (tid == 0) {
      int sel = s_ri[0];                     // in [0,1024) by construction
      s_sims[sel] = -INFINITY;
      s_top[t] = (sel < M) ? sel : (M - 1);  // clamp for gather safety
    }
    __syncthreads();
  }

  // r_pos tail of positions_k
  if (tid < TOPKN) {
    unsigned int d6 = O6E + (unsigned int)(b * SK + S + tid);
    if (d6 < outElems) out[d6] = mpos[s_top[tid]];
  }

  // gather retrieved rows: k_aug/v_aug[b,h,kk,:] = mem[im][h*64 .. h*64+63]
  // 2 * H * TOPK * 16 chunks = 5120 chunks per batch.
  const float4* mk4 = (const float4*)mkeys;
  const float4* mv4 = (const float4*)mvals;
  float4* o = (float4*)out;
  for (int c = tid; c < 5120; c += 256) {
    int isv = (c >= 2560);
    int cc = isv ? c - 2560 : c;
    int row = cc >> 4, ch = cc & 15;  // 16 chunks per 64-elem row
    int h = row / 10, kk = row - h * 10;
    int im = s_top[kk];               // clamped to [0, M)
    const float4* src = isv ? mv4 : mk4;
    unsigned int dst = (isv ? O3C : O2C) +
                       (unsigned int)((b * H + h) * BHSTR + kk * 16 + ch);
    if (dst < outChunks) o[dst] = src[(size_t)im * 256 + h * 16 + ch];
  }
}

// ---------------------------------------------------------------------------
extern "C" void kernel_launch(void* const* d_in, const int* in_sizes, int n_in,
                              void* d_out, int out_size, void* d_ws, size_t ws_size,
                              hipStream_t stream) {
  const float* in0 = (const float*)d_in[0];  // inputs  [4,2048,1024]
  const float* q   = (const float*)d_in[1];  // q       [4,16,2048,64]
  const float* k   = (const float*)d_in[2];  // k
  const float* v   = (const float*)d_in[3];  // v
  const float* am  = (const float*)d_in[4];  // attention_mask [4,2048]
  const float* mk  = (const float*)d_in[5];  // mem_keys   [1000,1024]
  const float* mv  = (const float*)d_in[6];  // mem_values [1000,1024]
  const float* mp  = (const float*)d_in[7];  // mem_positions [1000]
  // d_in[8] = seq_len_q (unused; S fixed at 2048)
  (void)in_sizes; (void)n_in; (void)ws_size;

  float* ws = (float*)d_ws;  // needs B*1024*4 = 16 KB; harness ws is larger

  fused_stage1<<<NSIMS + NCOPYBLK, 256, 0, stream>>>(
      in0, q, k, v, mk, (float*)d_out, ws, (unsigned int)out_size);
  fused_stage2<<<B, 256, 0, stream>>>(
      am, mk, mv, mp, ws, (float*)d_out, (unsigned int)out_size);
}

// Round 5
// 228.567 us; speedup vs baseline: 1.2689x; 1.2631x over previous
//
#include <hip/hip_runtime.h>

// Problem constants (fixed by setup_inputs) — ALL TENSORS ARE FLOAT32.
#define B 4
#define H 16
#define S 2048
#define D 64
#define M 1000
#define TOPKN 10
#define HID 1024   // H*D

// Flat output element offsets (f32 elements)
//  out0 inputs  [4,2048,1024]   @ 0
//  out1 q       [4,16,2048,64]  @ 8388608
//  out2 k_aug   [4,16,2058,64]  @ 16777216
//  out3 v_aug   [4,16,2058,64]  @ 25206784
//  out4 mask_aug[4,2058]        @ 33636352
//  out5 seq_len_k scalar        @ 33644584
//  out6 positions_k [4,2058]    @ 33644585   (total 33652817 elems)
#define O1E 8388608U
#define O2E 16777216U
#define O3E 25206784U
#define O4E 33636352U
#define O5E 33644584U
#define O6E 33644585U
#define TOTE 33652817U
// float4-chunk constants (4 f32 = 16 B per chunk)
#define O2C 4194304U   // out2 offset in chunks
#define O3C 6301696U   // out3 offset in chunks
#define BHSTR 32928U   // 2058*64/4 chunks per (b,h) in k_aug/v_aug

#define NSIMS 125  // 8 rows each = M exactly

// ---------------------------------------------------------------------------
// Sims kernel: sims[b][m] = cos-sim(query_key[b], mem_keys[m]) -> ws.
// One wave per 2 rows, coalesced row reads, shuffle reduce.
__global__ __launch_bounds__(256) void sims_kernel(
    const float* __restrict__ kin, const float* __restrict__ mkeys,
    float* __restrict__ ws) {
  const int blk = blockIdx.x;
  const int tid = threadIdx.x;

  __shared__ float4 s_q4[B][256];  // 4 query vectors, float4-packed (16 KB)
  __shared__ float s_qn[B];

  // Load all 4 query vectors: query_key[b][h*64+d] = k[b, h, S-1, d].
  for (int i = tid; i < B * 256; i += 256) {
    int b = i >> 8, c = i & 255;
    int h = c >> 4, dd = (c & 15) << 2;
    s_q4[b][c] = *(const float4*)(kin +
                                  ((size_t)(b * H + h) * S + (S - 1)) * D +
                                  dd);
  }
  __syncthreads();

  const int lane = tid & 63;
  const int w = tid >> 6;  // wave id 0..3

  // q norms: wave w reduces batch w
  {
    float ss = 0.f;
    for (int j = 0; j < 4; ++j) {
      float4 v = s_q4[w][lane + j * 64];
      ss += v.x * v.x + v.y * v.y + v.z * v.z + v.w * v.w;
    }
    for (int off = 32; off; off >>= 1) ss += __shfl_xor(ss, off);
    if (lane == 0) s_qn[w] = sqrtf(ss) + 1e-8f;
  }
  __syncthreads();

  // Each wave: 2 rows; lanes read the 4 KB row coalesced (64x16B chunks).
  const float4* mk4 = (const float4*)mkeys;
  for (int r = 0; r < 2; ++r) {
    const int m = blk * 8 + w * 2 + r;  // always < M (125*8 = 1000)
    float d0 = 0.f, d1 = 0.f, d2 = 0.f, d3 = 0.f, msq = 0.f;
#pragma unroll
    for (int j = 0; j < 4; ++j) {
      float4 ch = mk4[(size_t)m * 256 + lane + j * 64];
      float4 q0 = s_q4[0][lane + j * 64];
      float4 q1 = s_q4[1][lane + j * 64];
      float4 q2 = s_q4[2][lane + j * 64];
      float4 q3 = s_q4[3][lane + j * 64];
      d0 += q0.x * ch.x + q0.y * ch.y + q0.z * ch.z + q0.w * ch.w;
      d1 += q1.x * ch.x + q1.y * ch.y + q1.z * ch.z + q1.w * ch.w;
      d2 += q2.x * ch.x + q2.y * ch.y + q2.z * ch.z + q2.w * ch.w;
      d3 += q3.x * ch.x + q3.y * ch.y + q3.z * ch.z + q3.w * ch.w;
      msq += ch.x * ch.x + ch.y * ch.y + ch.z * ch.z + ch.w * ch.w;
    }
    for (int off = 32; off; off >>= 1) {
      d0 += __shfl_xor(d0, off);
      d1 += __shfl_xor(d1, off);
      d2 += __shfl_xor(d2, off);
      d3 += __shfl_xor(d3, off);
      msq += __shfl_xor(msq, off);
    }
    if (lane == 0) {
      float den = sqrtf(msq) + 1e-8f;  // same formula as proven kernel
      ws[0 * 1024 + m] = d0 / (s_qn[0] * den);
      ws[1 * 1024 + m] = d1 / (s_qn[1] * den);
      ws[2 * 1024 + m] = d2 / (s_qn[2] * den);
      ws[3 * 1024 + m] = d3 / (s_qn[3] * den);
    }
  }
}

// ---------------------------------------------------------------------------
// Stage 2: per-batch top-10 from ws + mask/positions/seq_len + gather.
__global__ __launch_bounds__(256) void fused_stage2(
    const float* __restrict__ amask, const float* __restrict__ mkeys,
    const float* __restrict__ mvals, const float* __restrict__ mpos,
    const float* __restrict__ ws, float* __restrict__ out,
    unsigned int outElems) {
  const int b = blockIdx.x;
  const int tid = threadIdx.x;
  const unsigned int outChunks = outElems >> 2;
  const int SK = S + TOPKN;  // 2058

  __shared__ float s_sims[1024];  // sims padded with -inf
  __shared__ float s_rv[256];
  __shared__ int s_ri[256];
  __shared__ int s_top[TOPKN];

  for (int i = tid; i < 1024; i += 256)
    s_sims[i] = (i < M) ? ws[b * 1024 + i] : -INFINITY;

  // mask_aug = [ones(K), mask]; positions_k[0:S] = arange(S)
  for (int i = tid; i < SK; i += 256) {
    unsigned int d4 = O4E + (unsigned int)(b * SK + i);
    if (d4 < outElems)
      out[d4] = (i < TOPKN) ? 1.0f : amask[b * S + (i - TOPKN)];
    unsigned int d6 = O6E + (unsigned int)(b * SK + i);
    if (i < S && d6 < outElems) out[d6] = (float)i;
  }
  if (b == 0 && tid == 0 && O5E < outElems)
    out[O5E] = 2064.0f;  // ref value is bf16-rounded 2058 (proven round 0)
  __syncthreads();

  // top-10: LDS-tree argmax x10 (ties -> lowest index, JAX semantics).
  // bi always a valid in-range index — NaN-proof, no sentinel can escape.
  for (int t = 0; t < TOPKN; ++t) {
    int base = tid * 4;
    float bv = s_sims[base];
    int bi = base;
    for (int j = 1; j < 4; ++j) {
      float v = s_sims[base + j];
      if (v > bv) { bv = v; bi = base + j; }  // '>' keeps lowest index
    }
    s_rv[tid] = bv;
    s_ri[tid] = bi;
    __syncthreads();
    for (int w = 128; w > 0; w >>= 1) {
      if (tid < w) {
        float ov = s_rv[tid + w];
        int oi = s_ri[tid + w];
        if (ov > s_rv[tid] || (ov == s_rv[tid] && oi < s_ri[tid])) {
          s_rv[tid] = ov;
          s_ri[tid] = oi;
        }
      }
      __syncthreads();
    }
    if (tid == 0) {
      int sel = s_ri[0];                     // in [0,1024) by construction
      s_sims[sel] = -INFINITY;
      s_top[t] = (sel < M) ? sel : (M - 1);  // clamp for gather safety
    }
    __syncthreads();
  }

  // r_pos tail of positions_k
  if (tid < TOPKN) {
    unsigned int d6 = O6E + (unsigned int)(b * SK + S + tid);
    if (d6 < outElems) out[d6] = mpos[s_top[tid]];
  }

  // gather retrieved rows: k_aug/v_aug[b,h,kk,:] = mem[im][h*64 .. h*64+63]
  // 2 * H * TOPK * 16 chunks = 5120 chunks per batch.
  const float4* mk4 = (const float4*)mkeys;
  const float4* mv4 = (const float4*)mvals;
  float4* o = (float4*)out;
  for (int c = tid; c < 5120; c += 256) {
    int isv = (c >= 2560);
    int cc = isv ? c - 2560 : c;
    int row = cc >> 4, ch = cc & 15;  // 16 chunks per 64-elem row
    int h = row / 10, kk = row - h * 10;
    int im = s_top[kk];               // clamped to [0, M)
    const float4* src = isv ? mv4 : mk4;
    unsigned int dst = (isv ? O3C : O2C) +
                       (unsigned int)((b * H + h) * BHSTR + kk * 16 + ch);
    if (dst < outChunks) o[dst] = src[(size_t)im * 256 + h * 16 + ch];
  }
}

// ---------------------------------------------------------------------------
extern "C" void kernel_launch(void* const* d_in, const int* in_sizes, int n_in,
                              void* d_out, int out_size, void* d_ws, size_t ws_size,
                              hipStream_t stream) {
  const float* in0 = (const float*)d_in[0];  // inputs  [4,2048,1024]
  const float* q   = (const float*)d_in[1];  // q       [4,16,2048,64]
  const float* k   = (const float*)d_in[2];  // k
  const float* v   = (const float*)d_in[3];  // v
  const float* am  = (const float*)d_in[4];  // attention_mask [4,2048]
  const float* mk  = (const float*)d_in[5];  // mem_keys   [1000,1024]
  const float* mv  = (const float*)d_in[6];  // mem_values [1000,1024]
  const float* mp  = (const float*)d_in[7];  // mem_positions [1000]
  // d_in[8] = seq_len_q (unused; S fixed at 2048)
  (void)in_sizes; (void)n_in; (void)ws_size;

  float* out = (float*)d_out;
  float* ws = (float*)d_ws;  // needs B*1024*4 = 16 KB; harness ws is larger

  // 1) sims (small kernel; reads k + mem_keys only)
  sims_kernel<<<NSIMS, 256, 0, stream>>>(k, mk, ws);

  // 2) bulk copies via the runtime's tuned blit path (A/B vs our 2.4 TB/s
  //    hand-rolled copies; fillBufferAligned demonstrates 6.6 TB/s writes).
  if ((unsigned int)out_size >= TOTE * 4U) {
    // out0 <- inputs, out1 <- q : contiguous 33.55 MB each
    hipMemcpyAsync(out, in0, (size_t)O1E * 4, hipMemcpyDeviceToDevice, stream);
    hipMemcpyAsync(out + O1E, q, (size_t)O1E * 4, hipMemcpyDeviceToDevice,
                   stream);
    // k_aug/v_aug bulk rows: 64 (b,h) panels; dst row starts 10 retrieved
    // rows (2560 B) into each 2058*64*4 = 526848 B panel. Disjoint from
    // stage2's writes (rows 0..9 of each panel).
    hipMemcpy2DAsync(out + O2E + TOPKN * D, (size_t)(S + TOPKN) * D * 4, k,
                     (size_t)S * D * 4, (size_t)S * D * 4, B * H,
                     hipMemcpyDeviceToDevice, stream);
    hipMemcpy2DAsync(out + O3E + TOPKN * D, (size_t)(S + TOPKN) * D * 4, v,
                     (size_t)S * D * 4, (size_t)S * D * 4, B * H,
                     hipMemcpyDeviceToDevice, stream);
  }

  // 3) top-k + retrieved-row gather + mask/positions/seq_len
  fused_stage2<<<B, 256, 0, stream>>>(am, mk, mv, mp, ws, out,
                                      (unsigned int)out_size);
}